// Round 1
// baseline (155.575 us; speedup 1.0000x reference)
//
#include <hip/hip_runtime.h>
#include <hip/hip_bf16.h>

#define IN_DIM 512
#define OUT_DIM 512

typedef unsigned short u16;
typedef __attribute__((ext_vector_type(4))) float f32x4;
typedef __attribute__((ext_vector_type(8))) __bf16 bf16x8;

__device__ __forceinline__ float softplus_f(float r) {
    return (r > 15.0f) ? r : log1pf(expf(r));
}

// ---------------------------------------------------------------------------
// Kernel 1: fold w = w_mu + softplus(w_rho)*w_eps -> bf16 [OUT][IN], and
//           b = b_mu + softplus(b_rho)*b_eps -> f32 [OUT], into workspace.
// ---------------------------------------------------------------------------
__global__ void prep_kernel(const float* __restrict__ wmu, const float* __restrict__ wrho,
                            const float* __restrict__ weps, const float* __restrict__ bmu,
                            const float* __restrict__ brho, const float* __restrict__ beps,
                            u16* __restrict__ wbf, float* __restrict__ bias) {
    int gid = blockIdx.x * 256 + threadIdx.x;
    int i4 = gid * 4;
    const float4 mu  = *(const float4*)(wmu + i4);
    const float4 rho = *(const float4*)(wrho + i4);
    const float4 ep  = *(const float4*)(weps + i4);
    union { __bf16 h[4]; uint2 u; } pk;
    pk.h[0] = (__bf16)(mu.x + softplus_f(rho.x) * ep.x);
    pk.h[1] = (__bf16)(mu.y + softplus_f(rho.y) * ep.y);
    pk.h[2] = (__bf16)(mu.z + softplus_f(rho.z) * ep.z);
    pk.h[3] = (__bf16)(mu.w + softplus_f(rho.w) * ep.w);
    *(uint2*)(wbf + i4) = pk.u;
    if (gid < OUT_DIM) {
        bias[gid] = bmu[gid] + softplus_f(brho[gid]) * beps[gid];
    }
}

// ---------------------------------------------------------------------------
// Kernel 2: y = x @ w^T + b, fused dropout.
// Grid: 2048 blocks (512 M-bands x 4 N-bands), 256 threads = 4 waves (2M x 2N).
// Block tile: 128x128, BK=64, K=512 (8 steps).
// A: f32 global -> regs -> cvt bf16 -> XOR-swizzled LDS (double-buffered).
// B: bf16 fragments loaded directly from L2-resident folded weights.
// ---------------------------------------------------------------------------
__global__ __launch_bounds__(256, 3) void bayes_gemm_kernel(
    const float* __restrict__ x, const float* __restrict__ du,
    const u16* __restrict__ wbf, const float* __restrict__ bias,
    float* __restrict__ out)
{
    __shared__ u16 ldsA[2][128 * 64];   // 2 x 16 KB bf16 A-tiles

    // XCD-aware swizzle: hardware round-robins raw id % 8 across XCDs.
    // lid = xcd*256 + slot  => each XCD gets a contiguous chunk of logical ids,
    // so the 4 N-siblings of an M-band run adjacently on one XCD (x-tile L2 reuse).
    const int raw   = blockIdx.x;
    const int lid   = (raw & 7) * 256 + (raw >> 3);
    const int mband = lid >> 2;      // 0..511
    const int nband = lid & 3;       // 0..3

    const int tid  = threadIdx.x;
    const int lane = tid & 63;
    const int wv   = tid >> 6;       // wave 0..3
    const int wm   = wv >> 1;        // 0..1
    const int wn   = wv & 1;         // 0..1
    const int l15  = lane & 15;
    const int lk   = lane >> 4;      // 0..3

    const int rowbase = mband * 128;
    const int wrow    = wm * 64;
    const int colbase = nband * 128 + wn * 64;

    // staging geometry: thread covers 4 rows (32*i + r0), 16B (8 bf16) per row
    const int t8 = tid & 7;
    const int r0 = tid >> 3;

    const float* xb = x + rowbase * IN_DIM;

    f32x4 acc[4][4] = {};

    float4 av[4][2];

    // ---- prologue: stage ks=0 into buffer 0
#pragma unroll
    for (int i = 0; i < 4; ++i) {
        int row = 32 * i + r0;
        const float* p = xb + row * IN_DIM + t8 * 8;
        av[i][0] = *(const float4*)p;
        av[i][1] = *(const float4*)(p + 4);
    }
#pragma unroll
    for (int i = 0; i < 4; ++i) {
        int row = 32 * i + r0;
        bf16x8 v;
        v[0] = (__bf16)av[i][0].x; v[1] = (__bf16)av[i][0].y;
        v[2] = (__bf16)av[i][0].z; v[3] = (__bf16)av[i][0].w;
        v[4] = (__bf16)av[i][1].x; v[5] = (__bf16)av[i][1].y;
        v[6] = (__bf16)av[i][1].z; v[7] = (__bf16)av[i][1].w;
        int off = row * 64 + ((t8 * 8) ^ ((row & 7) << 3));
        *(bf16x8*)&ldsA[0][off] = v;
    }
    __syncthreads();

    int buf = 0;
#pragma unroll
    for (int ks = 0; ks < 8; ++ks) {
        // issue next A-tile global loads early (latency hides under MFMA phase)
        if (ks < 7) {
#pragma unroll
            for (int i = 0; i < 4; ++i) {
                int row = 32 * i + r0;
                const float* p = xb + row * IN_DIM + (ks + 1) * 64 + t8 * 8;
                av[i][0] = *(const float4*)p;
                av[i][1] = *(const float4*)(p + 4);
            }
        }

#pragma unroll
        for (int kk = 0; kk < 2; ++kk) {
            // B fragments straight from L2-resident w (K-major rows, 16B/lane)
            bf16x8 bfr[4];
#pragma unroll
            for (int n = 0; n < 4; ++n) {
                const u16* wp = wbf + (colbase + n * 16 + l15) * IN_DIM
                              + ks * 64 + kk * 32 + lk * 8;
                bfr[n] = *(const bf16x8*)wp;
            }
            // A fragments from swizzled LDS
            bf16x8 afr[4];
#pragma unroll
            for (int m = 0; m < 4; ++m) {
                int row = wrow + m * 16 + l15;
                int off = row * 64 + (((kk * 32 + lk * 8)) ^ ((row & 7) << 3));
                afr[m] = *(const bf16x8*)&ldsA[buf][off];
            }
#pragma unroll
            for (int m = 0; m < 4; ++m)
#pragma unroll
                for (int n = 0; n < 4; ++n)
                    acc[m][n] = __builtin_amdgcn_mfma_f32_16x16x32_bf16(
                        afr[m], bfr[n], acc[m][n], 0, 0, 0);
        }

        if (ks < 7) {
            // convert + write next tile into the other buffer
#pragma unroll
            for (int i = 0; i < 4; ++i) {
                int row = 32 * i + r0;
                bf16x8 v;
                v[0] = (__bf16)av[i][0].x; v[1] = (__bf16)av[i][0].y;
                v[2] = (__bf16)av[i][0].z; v[3] = (__bf16)av[i][0].w;
                v[4] = (__bf16)av[i][1].x; v[5] = (__bf16)av[i][1].y;
                v[6] = (__bf16)av[i][1].z; v[7] = (__bf16)av[i][1].w;
                int off = row * 64 + ((t8 * 8) ^ ((row & 7) << 3));
                *(bf16x8*)&ldsA[buf ^ 1][off] = v;
            }
            __syncthreads();
            buf ^= 1;
        }
    }

    // ---- epilogue: bias + inverted dropout + store
    float bc[4];
#pragma unroll
    for (int n = 0; n < 4; ++n) bc[n] = bias[colbase + n * 16 + l15];

#pragma unroll
    for (int m = 0; m < 4; ++m) {
#pragma unroll
        for (int j = 0; j < 4; ++j) {
            int r = rowbase + wrow + m * 16 + lk * 4 + j;
            const float* dur = du + r * OUT_DIM;
            float* outr = out + r * OUT_DIM;
#pragma unroll
            for (int n = 0; n < 4; ++n) {
                int c = colbase + n * 16 + l15;
                float u = dur[c];
                float keep = (u >= 0.2f) ? 1.25f : 0.0f;
                outr[c] = (acc[m][n][j] + bc[n]) * keep;
            }
        }
    }
}

extern "C" void kernel_launch(void* const* d_in, const int* in_sizes, int n_in,
                              void* d_out, int out_size, void* d_ws, size_t ws_size,
                              hipStream_t stream) {
    const float* x    = (const float*)d_in[0];
    const float* wmu  = (const float*)d_in[1];
    const float* wrho = (const float*)d_in[2];
    const float* bmu  = (const float*)d_in[3];
    const float* brho = (const float*)d_in[4];
    const float* weps = (const float*)d_in[5];
    const float* beps = (const float*)d_in[6];
    const float* du   = (const float*)d_in[7];
    float* out = (float*)d_out;

    u16*   wbf  = (u16*)d_ws;
    float* bias = (float*)((char*)d_ws + OUT_DIM * IN_DIM * sizeof(u16));

    // 512*512 weights, 4 per thread -> 256 blocks x 256 threads
    prep_kernel<<<256, 256, 0, stream>>>(wmu, wrho, weps, bmu, brho, beps, wbf, bias);

    // 512 M-bands x 4 N-bands
    bayes_gemm_kernel<<<2048, 256, 0, stream>>>(x, du, wbf, bias, out);
}